// Round 4
// baseline (501.566 us; speedup 1.0000x reference)
//
#include <hip/hip_runtime.h>
#include <hip/hip_bf16.h>

#define DIM 512
#define BATCH 512
#define CCLS 100000
#define BM 128
#define BN 128
#define MT 4     // 512 / BM
#define NT 782   // ceil(100000/128)

typedef __attribute__((ext_vector_type(4))) float f32x4;
typedef __attribute__((ext_vector_type(4))) int i32x4;
typedef __attribute__((ext_vector_type(8))) int i32x8;

__device__ __forceinline__ void async_copy16(const unsigned char* g, unsigned char* l) {
  __builtin_amdgcn_global_load_lds((const __attribute__((address_space(1))) void*)g,
                                   (__attribute__((address_space(3))) void*)l, 16, 0, 0);
}

// One wave per row: read fp32 row, L2-normalize (fp32), write fp8 e4m3 row.
__global__ __launch_bounds__(256) void rownorm_fp8(const float* __restrict__ wt,
                                                   const float* __restrict__ x,
                                                   unsigned char* __restrict__ wn,
                                                   unsigned char* __restrict__ xn) {
  int wave = threadIdx.x >> 6;
  int lane = threadIdx.x & 63;
  int row4 = blockIdx.x * 4 + wave;
  const float* in;
  unsigned char* out;
  int row;
  if (row4 < CCLS) { in = wt; out = wn; row = row4; }
  else             { in = x;  out = xn; row = row4 - CCLS; }
  const float4* src = (const float4*)(in + (size_t)row * DIM);
  float4 v0 = src[2 * lane];
  float4 v1 = src[2 * lane + 1];
  float ss = v0.x*v0.x + v0.y*v0.y + v0.z*v0.z + v0.w*v0.w
           + v1.x*v1.x + v1.y*v1.y + v1.z*v1.z + v1.w*v1.w;
  #pragma unroll
  for (int off = 32; off > 0; off >>= 1) ss += __shfl_xor(ss, off, 64);
  float r = 1.0f / fmaxf(sqrtf(ss), 1e-12f);
  int p0 = __builtin_amdgcn_cvt_pk_fp8_f32(v0.x * r, v0.y * r, 0, false);
  p0     = __builtin_amdgcn_cvt_pk_fp8_f32(v0.z * r, v0.w * r, p0, true);
  int p1 = __builtin_amdgcn_cvt_pk_fp8_f32(v1.x * r, v1.y * r, 0, false);
  p1     = __builtin_amdgcn_cvt_pk_fp8_f32(v1.z * r, v1.w * r, p1, true);
  ((int2*)(out + (size_t)row * DIM))[lane] = make_int2(p0, p1);
}

// 128x128 tile MX-fp8 GEMM, K=512, BK=128 (4 tiles), 512 threads = 8 waves
// (2m x 4n), 64x32 per-wave tile -> acc 8 frags (32 VGPR), bf[2] persistent
// (16), af transient (8): total ~100 regs fits the (512,4) 128-VGPR cap ->
// 4 waves/SIMD, 2 blocks/CU (R0 occupancy) WITH the MX issue rate AND the
// 2-phase double-buffer prefetch (one vmcnt(0)+s_barrier per K-tile).
// Grid 3128 blocks, bijective XCD swizzle (3128 = 8*391) so the 4 mt-blocks
// sharing a B-tile land on one XCD's L2.
__global__ __launch_bounds__(512, 4) void cosface_gemm(
    const unsigned char* __restrict__ xn,
    const unsigned char* __restrict__ wn,
    const int* __restrict__ gt,
    float* __restrict__ partial,
    float* __restrict__ tgt) {
  __shared__ __align__(16) unsigned char lds_a[2][BM * 128];   // 32 KB
  __shared__ __align__(16) unsigned char lds_b[2][BN * 128];   // 32 KB
  __shared__ float lds_rowsum[BM];
  __shared__ int lds_gt[BM];

  const int tid = threadIdx.x;
  const int lane = tid & 63;
  const int w = tid >> 6;          // wave 0..7
  const int wm = w >> 2;           // 0..1  (64-row slice)
  const int wn_ = w & 3;           // 0..3  (32-col slice)

  // XCD-aware bijective chunked swizzle: 3128 blocks = 8 XCDs x 391.
  int flat = blockIdx.x;
  int f = (flat & 7) * 391 + (flat >> 3);
  const int mt = f & 3;            // 0..3
  const int nt = f >> 2;           // 0..781

  if (tid < BM) {
    lds_rowsum[tid] = 0.f;
    lds_gt[tid] = gt[mt * BM + tid];
  }

  // Staging: 16B chunk c -> row m = c>>3, slot qs = c&7, global chunk
  // qg = qs ^ (m&7). A: 1024 chunks (2/thread), B: 1024 chunks (2/thread).
  unsigned int oa[2];
  unsigned int ob[2];
  #pragma unroll
  for (int j = 0; j < 2; ++j) {
    int c = j * 512 + tid;
    int m = c >> 3;
    int qg = (c & 7) ^ (m & 7);
    oa[j] = (unsigned int)(mt * BM + m) * DIM + qg * 16;
    int rowB = nt * BN + m;
    if (rowB >= CCLS) rowB = CCLS - 1;   // clamp; excluded in epilogue
    ob[j] = (unsigned int)rowB * DIM + qg * 16;
  }

#define STAGE(sel, kk) do {                                                  \
    _Pragma("unroll")                                                        \
    for (int j = 0; j < 2; ++j)                                              \
      async_copy16(xn + oa[j] + (kk) * 128, &lds_a[sel][(j * 512 + w * 64) * 16]); \
    _Pragma("unroll")                                                        \
    for (int j = 0; j < 2; ++j)                                              \
      async_copy16(wn + ob[j] + (kk) * 128, &lds_b[sel][(j * 512 + w * 64) * 16]); \
  } while (0)

  f32x4 acc[4][2];
  #pragma unroll
  for (int i = 0; i < 4; ++i)
    #pragma unroll
    for (int j = 0; j < 2; ++j)
      acc[i][j] = (f32x4){0.f, 0.f, 0.f, 0.f};

  const int quad = lane >> 4;
  const int l15 = lane & 15;
  const int sw = l15 & 7;          // (row & 7) for all fragment rows
  const int c0 = quad * 2;         // global chunk of fragment low 16B
  const int c1 = quad * 2 + 1;     // high 16B

  // Prologue: stage tile 0, full drain (also covers lds_gt/rowsum init).
  STAGE(0, 0);
  __syncthreads();

  #pragma unroll
  for (int kk = 0; kk < 4; ++kk) {
    const int cur = kk & 1;
    if (kk < 3) STAGE(cur ^ 1, kk + 1);   // issue next tile's loads early

    // B fragments persistent (2 x i32x8 = 16 regs), A transient per i.
    i32x8 bf[2];
    #pragma unroll
    for (int j = 0; j < 2; ++j) {
      const unsigned char* pb = &lds_b[cur][(wn_ * 32 + j * 16 + l15) * 128];
      i32x4 lo = *(const i32x4*)(pb + ((c0 ^ sw) << 4));
      i32x4 hi = *(const i32x4*)(pb + ((c1 ^ sw) << 4));
      bf[j] = __builtin_shufflevector(lo, hi, 0, 1, 2, 3, 4, 5, 6, 7);
    }
    #pragma unroll
    for (int i = 0; i < 4; ++i) {
      const unsigned char* pa = &lds_a[cur][(wm * 64 + i * 16 + l15) * 128];
      i32x4 lo = *(const i32x4*)(pa + ((c0 ^ sw) << 4));
      i32x4 hi = *(const i32x4*)(pa + ((c1 ^ sw) << 4));
      i32x8 af = __builtin_shufflevector(lo, hi, 0, 1, 2, 3, 4, 5, 6, 7);
      #pragma unroll
      for (int j = 0; j < 2; ++j)
        acc[i][j] = __builtin_amdgcn_mfma_scale_f32_16x16x128_f8f6f4(
            af, bf[j], acc[i][j], 0, 0, 0, 127, 0, 127);
    }

    if (kk < 3) {
      // Publish this wave's next-tile LDS stores, then barrier. Reads of
      // lds_[cur] are complete (consumed by MFMA via lgkmcnt) before here.
      asm volatile("s_waitcnt vmcnt(0)" ::: "memory");
      __builtin_amdgcn_s_barrier();
      asm volatile("" ::: "memory");
    }
  }
#undef STAGE

  // Epilogue: logit = 64*cos (-22.4 at gt); rowsum += sum_n exp(logit-64)
  #pragma unroll
  for (int i = 0; i < 4; ++i) {
    #pragma unroll
    for (int reg = 0; reg < 4; ++reg) {
      int m_loc = wm * 64 + i * 16 + quad * 4 + reg;
      int m_g = mt * BM + m_loc;
      int gtm = lds_gt[m_loc];
      float s = 0.f;
      #pragma unroll
      for (int j = 0; j < 2; ++j) {
        int n_g = nt * BN + wn_ * 32 + j * 16 + l15;
        float logit = 64.f * acc[i][j][reg];
        if (n_g == gtm) {
          logit -= 64.f * 0.35f;
          tgt[m_g] = logit;
        }
        if (n_g < CCLS) s += __expf(logit - 64.f);
      }
      #pragma unroll
      for (int off = 1; off < 16; off <<= 1) s += __shfl_xor(s, off, 64);
      if (l15 == 0) atomicAdd(&lds_rowsum[m_loc], s);
    }
  }
  __syncthreads();
  if (tid < BM)
    partial[(size_t)(mt * BM + tid) * NT + nt] = lds_rowsum[tid];
}

// One wave per row m: sum partial[m][0..NT) (contiguous), emit nll[m].
__global__ __launch_bounds__(64) void nll_rows(const float* __restrict__ partial,
                                               const float* __restrict__ tgt,
                                               float* __restrict__ nll) {
  int m = blockIdx.x;
  int lane = threadIdx.x;
  const float* row = partial + (size_t)m * NT;
  float s = 0.f;
  for (int t = lane; t < NT; t += 64) s += row[t];
  #pragma unroll
  for (int off = 32; off > 0; off >>= 1) s += __shfl_xor(s, off, 64);
  if (lane == 0) nll[m] = (logf(s) + 64.f) - tgt[m];
}

__global__ __launch_bounds__(512) void reduce_mean(const float* __restrict__ nll,
                                                   float* __restrict__ out) {
  __shared__ float red[BATCH];
  int m = threadIdx.x;
  red[m] = nll[m];
  __syncthreads();
  for (int k = 256; k > 0; k >>= 1) {
    if (m < k) red[m] += red[m + k];
    __syncthreads();
  }
  if (m == 0) out[0] = red[0] * (1.0f / BATCH);
}

extern "C" void kernel_launch(void* const* d_in, const int* in_sizes, int n_in,
                              void* d_out, int out_size, void* d_ws, size_t ws_size,
                              hipStream_t stream) {
  const float* x  = (const float*)d_in[0];
  const int*   gt = (const int*)d_in[1];
  const float* wt = (const float*)d_in[2];
  float* out = (float*)d_out;

  char* ws = (char*)d_ws;
  unsigned char* wn = (unsigned char*)ws;                      //  51,200,000 B
  unsigned char* xn = (unsigned char*)(ws + 51200000);         //     262,144 B
  float* partial    = (float*)(ws + 51462144);                 //   1,601,536 B
  float* tgt        = (float*)(ws + 53063680);                 //       2,048 B
  float* nll        = (float*)(ws + 53065728);                 //       2,048 B

  rownorm_fp8<<<(CCLS + BATCH) / 4, 256, 0, stream>>>(wt, x, wn, xn);
  cosface_gemm<<<MT * NT, 512, 0, stream>>>(xn, wn, gt, partial, tgt);
  nll_rows<<<BATCH, 64, 0, stream>>>(partial, tgt, nll);
  reduce_mean<<<1, BATCH, 0, stream>>>(nll, out);
}

// Round 5
// 389.538 us; speedup vs baseline: 1.2876x; 1.2876x over previous
//
#include <hip/hip_runtime.h>
#include <hip/hip_bf16.h>

#define DIM 512
#define BATCH 512
#define CCLS 100000
#define BM 128
#define BN 64
#define MT 4      // 512 / BM
#define NT 1563   // ceil(100000/64)

typedef __attribute__((ext_vector_type(4))) float f32x4;
typedef __attribute__((ext_vector_type(4))) int i32x4;
typedef __attribute__((ext_vector_type(8))) int i32x8;

__device__ __forceinline__ void async_copy16(const unsigned char* g, unsigned char* l) {
  __builtin_amdgcn_global_load_lds((const __attribute__((address_space(1))) void*)g,
                                   (__attribute__((address_space(3))) void*)l, 16, 0, 0);
}

// One wave per row: read fp32 row, L2-normalize (fp32), write fp8 e4m3 row.
__global__ __launch_bounds__(256) void rownorm_fp8(const float* __restrict__ wt,
                                                   const float* __restrict__ x,
                                                   unsigned char* __restrict__ wn,
                                                   unsigned char* __restrict__ xn) {
  int wave = threadIdx.x >> 6;
  int lane = threadIdx.x & 63;
  int row4 = blockIdx.x * 4 + wave;
  const float* in;
  unsigned char* out;
  int row;
  if (row4 < CCLS) { in = wt; out = wn; row = row4; }
  else             { in = x;  out = xn; row = row4 - CCLS; }
  const float4* src = (const float4*)(in + (size_t)row * DIM);
  float4 v0 = src[2 * lane];
  float4 v1 = src[2 * lane + 1];
  float ss = v0.x*v0.x + v0.y*v0.y + v0.z*v0.z + v0.w*v0.w
           + v1.x*v1.x + v1.y*v1.y + v1.z*v1.z + v1.w*v1.w;
  #pragma unroll
  for (int off = 32; off > 0; off >>= 1) ss += __shfl_xor(ss, off, 64);
  float r = 1.0f / fmaxf(sqrtf(ss), 1e-12f);
  int p0 = __builtin_amdgcn_cvt_pk_fp8_f32(v0.x * r, v0.y * r, 0, false);
  p0     = __builtin_amdgcn_cvt_pk_fp8_f32(v0.z * r, v0.w * r, p0, true);
  int p1 = __builtin_amdgcn_cvt_pk_fp8_f32(v1.x * r, v1.y * r, 0, false);
  p1     = __builtin_amdgcn_cvt_pk_fp8_f32(v1.z * r, v1.w * r, p1, true);
  ((int2*)(out + (size_t)row * DIM))[lane] = make_int2(p0, p1);
}

// 128x64 tile MX-fp8 GEMM, K=512, BK=128 (4 tiles), 256 threads = 4 waves
// (2m x 2n), 64x32 per-wave tile. mfma_scale needs the 256-VGPR-cap regime
// (cap 128 => accum-split spill, rounds 1/4: VGPR_Count=64 + 450 MB scratch),
// so: 256-thread blocks under __launch_bounds__(256,2); small live set
// (acc 32 + bf 16 + af 8) should land ~110-170 actual VGPRs -> 3 waves/SIMD,
// and dbuf LDS 48 KB -> 3 blocks/CU. Cross-block TLP hides the per-tile
// vmcnt(0)+s_barrier drain; 2-phase prefetch hides staging issue latency.
// Bijective XCD swizzle: 4 mt-blocks sharing a B-tile are wgid-consecutive.
__global__ __launch_bounds__(256, 2) void cosface_gemm(
    const unsigned char* __restrict__ xn,
    const unsigned char* __restrict__ wn,
    const int* __restrict__ gt,
    float* __restrict__ partial,
    float* __restrict__ tgt) {
  __shared__ __align__(16) unsigned char lds_a[2][BM * 128];   // 32 KB
  __shared__ __align__(16) unsigned char lds_b[2][BN * 128];   // 16 KB
  __shared__ float lds_rowsum[BM];
  __shared__ int lds_gt[BM];

  const int tid = threadIdx.x;
  const int lane = tid & 63;
  const int w = tid >> 6;          // wave 0..3
  const int wm = w >> 1;           // 0..1  (64-row slice)
  const int wn_ = w & 1;           // 0..1  (32-col slice)

  // Bijective XCD swizzle: 6252 = 8*781 + 4 (xcd 0..3 get 782, 4..7 get 781).
  int flat = blockIdx.x;
  int xcd = flat & 7;
  int idx = flat >> 3;
  int f = (xcd < 4 ? xcd * 782 : 4 * 782 + (xcd - 4) * 781) + idx;
  const int mt = f & 3;            // 0..3
  const int nt = f >> 2;           // 0..1562

  if (tid < BM) {
    lds_rowsum[tid] = 0.f;
    lds_gt[tid] = gt[mt * BM + tid];
  }

  // Staging: 16B chunk c -> row m = c>>3, slot qs = c&7, global chunk
  // qg = qs ^ (m&7). A: 1024 chunks (4/thread), B: 512 chunks (2/thread).
  unsigned int oa[4];
  unsigned int ob[2];
  #pragma unroll
  for (int j = 0; j < 4; ++j) {
    int c = j * 256 + tid;
    int m = c >> 3;
    int qg = (c & 7) ^ (m & 7);
    oa[j] = (unsigned int)(mt * BM + m) * DIM + qg * 16;
  }
  #pragma unroll
  for (int j = 0; j < 2; ++j) {
    int c = j * 256 + tid;
    int m = c >> 3;
    int qg = (c & 7) ^ (m & 7);
    int rowB = nt * BN + m;
    if (rowB >= CCLS) rowB = CCLS - 1;   // clamp; excluded in epilogue
    ob[j] = (unsigned int)rowB * DIM + qg * 16;
  }

#define STAGE(sel, kk) do {                                                  \
    _Pragma("unroll")                                                        \
    for (int j = 0; j < 4; ++j)                                              \
      async_copy16(xn + oa[j] + (kk) * 128, &lds_a[sel][(j * 256 + w * 64) * 16]); \
    _Pragma("unroll")                                                        \
    for (int j = 0; j < 2; ++j)                                              \
      async_copy16(wn + ob[j] + (kk) * 128, &lds_b[sel][(j * 256 + w * 64) * 16]); \
  } while (0)

  f32x4 acc[4][2];
  #pragma unroll
  for (int i = 0; i < 4; ++i)
    #pragma unroll
    for (int j = 0; j < 2; ++j)
      acc[i][j] = (f32x4){0.f, 0.f, 0.f, 0.f};

  const int quad = lane >> 4;
  const int l15 = lane & 15;
  const int sw = l15 & 7;          // (row & 7) for all fragment rows
  const int c0 = quad * 2;         // global chunk of fragment low 16B
  const int c1 = quad * 2 + 1;     // high 16B

  // Prologue: stage tile 0, full drain (also covers lds_gt/rowsum init).
  STAGE(0, 0);
  __syncthreads();

  #pragma unroll
  for (int kk = 0; kk < 4; ++kk) {
    const int cur = kk & 1;
    if (kk < 3) STAGE(cur ^ 1, kk + 1);   // issue next tile's loads early

    // B fragments persistent (2 x i32x8 = 16 regs), A transient per i.
    i32x8 bf[2];
    #pragma unroll
    for (int j = 0; j < 2; ++j) {
      const unsigned char* pb = &lds_b[cur][(wn_ * 32 + j * 16 + l15) * 128];
      i32x4 lo = *(const i32x4*)(pb + ((c0 ^ sw) << 4));
      i32x4 hi = *(const i32x4*)(pb + ((c1 ^ sw) << 4));
      bf[j] = __builtin_shufflevector(lo, hi, 0, 1, 2, 3, 4, 5, 6, 7);
    }
    #pragma unroll
    for (int i = 0; i < 4; ++i) {
      const unsigned char* pa = &lds_a[cur][(wm * 64 + i * 16 + l15) * 128];
      i32x4 lo = *(const i32x4*)(pa + ((c0 ^ sw) << 4));
      i32x4 hi = *(const i32x4*)(pa + ((c1 ^ sw) << 4));
      i32x8 af = __builtin_shufflevector(lo, hi, 0, 1, 2, 3, 4, 5, 6, 7);
      #pragma unroll
      for (int j = 0; j < 2; ++j)
        acc[i][j] = __builtin_amdgcn_mfma_scale_f32_16x16x128_f8f6f4(
            af, bf[j], acc[i][j], 0, 0, 0, 127, 0, 127);
    }

    if (kk < 3) {
      // Publish this wave's next-tile LDS stores, then barrier. Reads of
      // lds_[cur] are complete (consumed by MFMA via lgkmcnt) before here.
      asm volatile("s_waitcnt vmcnt(0)" ::: "memory");
      __builtin_amdgcn_s_barrier();
      asm volatile("" ::: "memory");
    }
  }
#undef STAGE

  // Epilogue: logit = 64*cos (-22.4 at gt); rowsum += sum_n exp(logit-64)
  #pragma unroll
  for (int i = 0; i < 4; ++i) {
    #pragma unroll
    for (int reg = 0; reg < 4; ++reg) {
      int m_loc = wm * 64 + i * 16 + quad * 4 + reg;
      int m_g = mt * BM + m_loc;
      int gtm = lds_gt[m_loc];
      float s = 0.f;
      #pragma unroll
      for (int j = 0; j < 2; ++j) {
        int n_g = nt * BN + wn_ * 32 + j * 16 + l15;
        float logit = 64.f * acc[i][j][reg];
        if (n_g == gtm) {
          logit -= 64.f * 0.35f;
          tgt[m_g] = logit;
        }
        if (n_g < CCLS) s += __expf(logit - 64.f);
      }
      #pragma unroll
      for (int off = 1; off < 16; off <<= 1) s += __shfl_xor(s, off, 64);
      if (l15 == 0) atomicAdd(&lds_rowsum[m_loc], s);
    }
  }
  __syncthreads();
  if (tid < BM)
    partial[(size_t)(mt * BM + tid) * NT + nt] = lds_rowsum[tid];
}

// One wave per row m: sum partial[m][0..NT) (contiguous), emit nll[m].
__global__ __launch_bounds__(64) void nll_rows(const float* __restrict__ partial,
                                               const float* __restrict__ tgt,
                                               float* __restrict__ nll) {
  int m = blockIdx.x;
  int lane = threadIdx.x;
  const float* row = partial + (size_t)m * NT;
  float s = 0.f;
  for (int t = lane; t < NT; t += 64) s += row[t];
  #pragma unroll
  for (int off = 32; off > 0; off >>= 1) s += __shfl_xor(s, off, 64);
  if (lane == 0) nll[m] = (logf(s) + 64.f) - tgt[m];
}

__global__ __launch_bounds__(512) void reduce_mean(const float* __restrict__ nll,
                                                   float* __restrict__ out) {
  __shared__ float red[BATCH];
  int m = threadIdx.x;
  red[m] = nll[m];
  __syncthreads();
  for (int k = 256; k > 0; k >>= 1) {
    if (m < k) red[m] += red[m + k];
    __syncthreads();
  }
  if (m == 0) out[0] = red[0] * (1.0f / BATCH);
}

extern "C" void kernel_launch(void* const* d_in, const int* in_sizes, int n_in,
                              void* d_out, int out_size, void* d_ws, size_t ws_size,
                              hipStream_t stream) {
  const float* x  = (const float*)d_in[0];
  const int*   gt = (const int*)d_in[1];
  const float* wt = (const float*)d_in[2];
  float* out = (float*)d_out;

  char* ws = (char*)d_ws;
  unsigned char* wn = (unsigned char*)ws;                      //  51,200,000 B
  unsigned char* xn = (unsigned char*)(ws + 51200000);         //     262,144 B
  float* partial    = (float*)(ws + 51462144);                 //   3,201,024 B (512*1563*4)
  float* tgt        = (float*)(ws + 54663168);                 //       2,048 B
  float* nll        = (float*)(ws + 54665216);                 //       2,048 B

  rownorm_fp8<<<(CCLS + BATCH) / 4, 256, 0, stream>>>(wt, x, wn, xn);
  cosface_gemm<<<MT * NT, 256, 0, stream>>>(xn, wn, gt, partial, tgt);
  nll_rows<<<BATCH, 64, 0, stream>>>(partial, tgt, nll);
  reduce_mean<<<1, BATCH, 0, stream>>>(nll, out);
}